// Round 5
// baseline (345.373 us; speedup 1.0000x reference)
//
#include <hip/hip_runtime.h>
#include <math.h>

// EnergySRB, R10: ABLATION ROUND (deliberate measurement; total dur will rise).
// R5-R9 post-mortem: dur pinned at 80-86us across (a) 16 vs 32 waves/CU,
// (b) four different load schedules incl. guaranteed-deep asm pipeline,
// (c) HBM-cold vs L3-warm (rocprof replay, FETCH~0) -> NOT latency, NOT HBM
// BW, NOT occupancy. No pipe >20% busy in counters; budget arithmetic is
// missing a 3-4x cost somewhere. Per the ablate-before-optimize rule, this
// round adds 3 no-output ablation kernels (asm-sink kept-alive, zero global
// writes) after the unchanged real pipeline:
//   abl_stream16  : loads only                 -> pure 3-stream read cost
//   abl_gds_nomath: loads+gather+bperm+atomic  -> DS-pipe cost (no math)
//   abl_math_nods : loads+full math, no DS ops -> VALU/TRANS cost
// Next round reads their durations from the top-5 table (names visible) and
// from total-dur subtraction, then targets the dominant component.

#define NT        1024
#define NBLK      512
#define SCALE_F   134217728.0f              // 2^27
#define INV_SCALE 7.450580596923828125e-9   // 2^-27, exact in double

typedef unsigned v4u __attribute__((ext_vector_type(4)));
typedef float    v4f __attribute__((ext_vector_type(4)));

// ---------------------------------------------------------------------------
__global__ void pack_species_kernel(const int* __restrict__ sp,
                                    unsigned* __restrict__ packed, int nwords) {
    int w = blockIdx.x * blockDim.x + threadIdx.x;
    if (w >= nwords) return;
    const int4* p4 = (const int4*)(sp + (w << 4));
    int4 a = p4[0], b = p4[1], c = p4[2], d = p4[3];
    unsigned v =
        (unsigned)(a.x & 3)        | ((unsigned)(a.y & 3) << 2)  |
        ((unsigned)(a.z & 3) << 4) | ((unsigned)(a.w & 3) << 6)  |
        ((unsigned)(b.x & 3) << 8) | ((unsigned)(b.y & 3) << 10) |
        ((unsigned)(b.z & 3) << 12)| ((unsigned)(b.w & 3) << 14) |
        ((unsigned)(c.x & 3) << 16)| ((unsigned)(c.y & 3) << 18) |
        ((unsigned)(c.z & 3) << 20)| ((unsigned)(c.w & 3) << 22) |
        ((unsigned)(d.x & 3) << 24)| ((unsigned)(d.y & 3) << 26) |
        ((unsigned)(d.z & 3) << 28)| ((unsigned)(d.w & 3) << 30);
    packed[w] = v;
}

// ---------------------------------------------------------------------------
__global__ void init_kernel(const int* __restrict__ species,
                            float* __restrict__ out,
                            unsigned long long* __restrict__ acc,
                            int n_species, int n_mol) {
    int i = blockIdx.x * blockDim.x + threadIdx.x;
    if (i < n_species) out[i] = (float)species[i];
    if (i < n_mol)     acc[i] = 0ull;
}

// ---------------------------------------------------------------------------
#define GLOAD(d0, d1, dd, OFF)                                              \
    asm volatile("global_load_dwordx4 %0, %3, %4\n\t"                        \
                 "global_load_dwordx4 %1, %3, %5\n\t"                        \
                 "global_load_dwordx4 %2, %3, %6"                            \
                 : "=&v"(d0), "=&v"(d1), "=&v"(dd)                           \
                 : "v"(OFF), "s"(pb0), "s"(pb1), "s"(pbd)                    \
                 : "memory")

#define VWAIT(n)                                                             \
    do {                                                                     \
        asm volatile("s_waitcnt vmcnt(" #n ")" ::: "memory");                \
        __builtin_amdgcn_sched_barrier(0);                                   \
    } while (0)

// ---------------------------------------------------------------------------
// REAL kernel (unchanged R9). Requires nit>=2, nit%3==2; bench nit=8.
__global__ __launch_bounds__(NT, 8)
void srb_fused_u32_pipe(const unsigned* __restrict__ packed_ws,
                        const int* __restrict__ ai,
                        const float* __restrict__ dist,
                        const float* __restrict__ pre_tab,
                        const float* __restrict__ dfac_tab,
                        unsigned long long* __restrict__ acc,
                        int P, int mol_shift, int nit) {
    __shared__ unsigned packed[16384];
    __shared__ unsigned binsu[4096];

    const int t = threadIdx.x;
    for (int i = t; i < 4096; i += NT) binsu[i] = 0u;
    const float myPre  = -pre_tab[t & 15];
    const float myDfac =  dfac_tab[t & 15];
    {
        int4* dst = (int4*)packed;
        const int4* src = (const int4*)packed_ws;
        for (int i = t; i < 4096; i += NT) dst[i] = src[i];
    }
    __syncthreads();

    const float a2b   = (float)1.8897261258369282;
    const float rc    = (float)(5.2 * 1.8897261258369282);
    const float rcinv = (float)(1.0 / (5.2 * 1.8897261258369282));

    const int      stride = (int)gridDim.x * NT;
    const unsigned stepB  = (unsigned)stride * 16u;
    unsigned off = (unsigned)((int)blockIdx.x * NT + t) * 16u;

    const char* pb0 = (const char*)ai;
    const char* pb1 = (const char*)(ai + P);
    const char* pbd = (const char*)dist;

    #define PBODY(X0, X1, XD)                                                \
    do {                                                                     \
        unsigned a0_[4] = { X0[0], X0[1], X0[2], X0[3] };                    \
        unsigned a1_[4] = { X1[0], X1[1], X1[2], X1[3] };                    \
        float    dd_[4] = { XD[0], XD[1], XD[2], XD[3] };                    \
        unsigned w0_[4], w1_[4];                                             \
        _Pragma("unroll")                                                    \
        for (int k = 0; k < 4; ++k) w0_[k] = packed[a0_[k] >> 4];            \
        _Pragma("unroll")                                                    \
        for (int k = 0; k < 4; ++k) w1_[k] = packed[a1_[k] >> 4];            \
        float pr_[4], df_[4];                                                \
        _Pragma("unroll")                                                    \
        for (int k = 0; k < 4; ++k) {                                        \
            unsigned s0 = (w0_[k] >> ((a0_[k] & 15u) << 1)) & 3u;            \
            unsigned s1 = (w1_[k] >> ((a1_[k] & 15u) << 1)) & 3u;            \
            int idx = (int)((s0 << 2) | s1);                                 \
            pr_[k] = __shfl(myPre,  idx, 64);                                \
            df_[k] = __shfl(myDfac, idx, 64);                                \
        }                                                                    \
        unsigned q_[4];                                                      \
        _Pragma("unroll")                                                    \
        for (int k = 0; k < 4; ++k) {                                        \
            float db  = dd_[k] * a2b;                                        \
            float x   = db * rcinv;                                          \
            float arg = df_[k] * db + (1.0f - 1.0f / (1.0f - x * x));        \
            float mag = pr_[k] * __expf(arg);                                \
            mag = (db < rc) ? mag : 0.0f;                                    \
            q_[k] = (unsigned)(mag * SCALE_F);                               \
        }                                                                    \
        _Pragma("unroll")                                                    \
        for (int k = 0; k < 4; ++k)                                          \
            atomicAdd(&binsu[a0_[k] >> mol_shift], q_[k]);                   \
    } while (0)

    v4u A0, A1, B0, B1, C0, C1;
    v4f AD, BDv, CD;

    GLOAD(A0, A1, AD, off);  off += stepB;
    GLOAD(B0, B1, BDv, off); off += stepB;

    int i = 0;
    #pragma unroll 1
    for (; i + 4 < nit; i += 3) {
        GLOAD(C0, C1, CD, off);  off += stepB;
        VWAIT(6);
        PBODY(A0, A1, AD);
        GLOAD(A0, A1, AD, off);  off += stepB;
        VWAIT(6);
        PBODY(B0, B1, BDv);
        GLOAD(B0, B1, BDv, off); off += stepB;
        VWAIT(6);
        PBODY(C0, C1, CD);
    }
    VWAIT(3);
    PBODY(A0, A1, AD);
    VWAIT(0);
    PBODY(B0, B1, BDv);
    #undef PBODY

    __syncthreads();
    for (int i2 = t; i2 < 4096; i2 += NT) {
        unsigned v = binsu[i2];
        if (v) atomicAdd(&acc[i2], (unsigned long long)v);
    }
}

// ---------------------------------------------------------------------------
// ABLATION A: loads only. Same pipeline, buffers sunk. No global writes.
__global__ __launch_bounds__(NT, 8)
void abl_stream16(const unsigned* __restrict__ packed_ws,
                  const int* __restrict__ ai,
                  const float* __restrict__ dist,
                  int P, int nit) {
    __shared__ unsigned packed[16384];
    __shared__ unsigned binsu[4096];
    const int t = threadIdx.x;
    for (int i = t; i < 4096; i += NT) binsu[i] = 0u;
    {
        int4* dst = (int4*)packed;
        const int4* src = (const int4*)packed_ws;
        for (int i = t; i < 4096; i += NT) dst[i] = src[i];
    }
    __syncthreads();

    const int      stride = (int)gridDim.x * NT;
    const unsigned stepB  = (unsigned)stride * 16u;
    unsigned off = (unsigned)((int)blockIdx.x * NT + t) * 16u;
    const char* pb0 = (const char*)ai;
    const char* pb1 = (const char*)(ai + P);
    const char* pbd = (const char*)dist;

    #define SINKB(X0, X1, XD) \
        asm volatile("" :: "v"(X0), "v"(X1), "v"(XD))

    v4u A0, A1, B0, B1, C0, C1;
    v4f AD, BDv, CD;
    GLOAD(A0, A1, AD, off);  off += stepB;
    GLOAD(B0, B1, BDv, off); off += stepB;
    int i = 0;
    #pragma unroll 1
    for (; i + 4 < nit; i += 3) {
        GLOAD(C0, C1, CD, off);  off += stepB;
        VWAIT(6); SINKB(A0, A1, AD);
        GLOAD(A0, A1, AD, off);  off += stepB;
        VWAIT(6); SINKB(B0, B1, BDv);
        GLOAD(B0, B1, BDv, off); off += stepB;
        VWAIT(6); SINKB(C0, C1, CD);
    }
    VWAIT(3); SINKB(A0, A1, AD);
    VWAIT(0); SINKB(B0, B1, BDv);
    #undef SINKB

    __syncthreads();
    unsigned keep = binsu[t & 4095] ^ packed[t & 16383];
    asm volatile("" :: "v"(keep));
}

// ---------------------------------------------------------------------------
// ABLATION B: loads + gathers + bpermutes + LDS atomics; Phase-3 math gone.
__global__ __launch_bounds__(NT, 8)
void abl_gds_nomath(const unsigned* __restrict__ packed_ws,
                    const int* __restrict__ ai,
                    const float* __restrict__ dist,
                    const float* __restrict__ pre_tab,
                    const float* __restrict__ dfac_tab,
                    int P, int mol_shift, int nit) {
    __shared__ unsigned packed[16384];
    __shared__ unsigned binsu[4096];
    const int t = threadIdx.x;
    for (int i = t; i < 4096; i += NT) binsu[i] = 0u;
    const float myPre  = -pre_tab[t & 15];
    const float myDfac =  dfac_tab[t & 15];
    {
        int4* dst = (int4*)packed;
        const int4* src = (const int4*)packed_ws;
        for (int i = t; i < 4096; i += NT) dst[i] = src[i];
    }
    __syncthreads();

    const int      stride = (int)gridDim.x * NT;
    const unsigned stepB  = (unsigned)stride * 16u;
    unsigned off = (unsigned)((int)blockIdx.x * NT + t) * 16u;
    const char* pb0 = (const char*)ai;
    const char* pb1 = (const char*)(ai + P);
    const char* pbd = (const char*)dist;

    #define DSBODY(X0, X1, XD)                                               \
    do {                                                                     \
        unsigned a0_[4] = { X0[0], X0[1], X0[2], X0[3] };                    \
        unsigned a1_[4] = { X1[0], X1[1], X1[2], X1[3] };                    \
        unsigned w0_[4], w1_[4];                                             \
        _Pragma("unroll")                                                    \
        for (int k = 0; k < 4; ++k) w0_[k] = packed[a0_[k] >> 4];            \
        _Pragma("unroll")                                                    \
        for (int k = 0; k < 4; ++k) w1_[k] = packed[a1_[k] >> 4];            \
        float pr_[4], df_[4];                                                \
        _Pragma("unroll")                                                    \
        for (int k = 0; k < 4; ++k) {                                        \
            unsigned s0 = (w0_[k] >> ((a0_[k] & 15u) << 1)) & 3u;            \
            unsigned s1 = (w1_[k] >> ((a1_[k] & 15u) << 1)) & 3u;            \
            int idx = (int)((s0 << 2) | s1);                                 \
            pr_[k] = __shfl(myPre,  idx, 64);                                \
            df_[k] = __shfl(myDfac, idx, 64);                                \
        }                                                                    \
        _Pragma("unroll")                                                    \
        for (int k = 0; k < 4; ++k) {                                        \
            unsigned q = __float_as_uint(pr_[k]) ^ __float_as_uint(df_[k]);  \
            atomicAdd(&binsu[a0_[k] >> mol_shift], q);                       \
        }                                                                    \
        asm volatile("" :: "v"(XD));                                         \
    } while (0)

    v4u A0, A1, B0, B1, C0, C1;
    v4f AD, BDv, CD;
    GLOAD(A0, A1, AD, off);  off += stepB;
    GLOAD(B0, B1, BDv, off); off += stepB;
    int i = 0;
    #pragma unroll 1
    for (; i + 4 < nit; i += 3) {
        GLOAD(C0, C1, CD, off);  off += stepB;
        VWAIT(6); DSBODY(A0, A1, AD);
        GLOAD(A0, A1, AD, off);  off += stepB;
        VWAIT(6); DSBODY(B0, B1, BDv);
        GLOAD(B0, B1, BDv, off); off += stepB;
        VWAIT(6); DSBODY(C0, C1, CD);
    }
    VWAIT(3); DSBODY(A0, A1, AD);
    VWAIT(0); DSBODY(B0, B1, BDv);
    #undef DSBODY

    __syncthreads();
    unsigned keep = binsu[t & 4095];
    asm volatile("" :: "v"(keep));
}

// ---------------------------------------------------------------------------
// ABLATION C: loads + full VALU/div/exp chain, register-constant table,
// ZERO DS ops in the loop. Results sunk.
__global__ __launch_bounds__(NT, 8)
void abl_math_nods(const unsigned* __restrict__ packed_ws,
                   const int* __restrict__ ai,
                   const float* __restrict__ dist,
                   const float* __restrict__ pre_tab,
                   const float* __restrict__ dfac_tab,
                   int P, int nit) {
    __shared__ unsigned packed[16384];
    __shared__ unsigned binsu[4096];
    const int t = threadIdx.x;
    for (int i = t; i < 4096; i += NT) binsu[i] = 0u;
    const float myPre  = -pre_tab[t & 15];
    const float myDfac =  dfac_tab[t & 15];
    {
        int4* dst = (int4*)packed;
        const int4* src = (const int4*)packed_ws;
        for (int i = t; i < 4096; i += NT) dst[i] = src[i];
    }
    __syncthreads();

    const float a2b   = (float)1.8897261258369282;
    const float rc    = (float)(5.2 * 1.8897261258369282);
    const float rcinv = (float)(1.0 / (5.2 * 1.8897261258369282));

    const int      stride = (int)gridDim.x * NT;
    const unsigned stepB  = (unsigned)stride * 16u;
    unsigned off = (unsigned)((int)blockIdx.x * NT + t) * 16u;
    const char* pb0 = (const char*)ai;
    const char* pb1 = (const char*)(ai + P);
    const char* pbd = (const char*)dist;

    #define MBODY(X0, X1, XD)                                                \
    do {                                                                     \
        float dd_[4] = { XD[0], XD[1], XD[2], XD[3] };                       \
        unsigned q_[4];                                                      \
        _Pragma("unroll")                                                    \
        for (int k = 0; k < 4; ++k) {                                        \
            float db  = dd_[k] * a2b;                                        \
            float x   = db * rcinv;                                          \
            float arg = myDfac * db + (1.0f - 1.0f / (1.0f - x * x));        \
            float mag = myPre * __expf(arg);                                 \
            mag = (db < rc) ? mag : 0.0f;                                    \
            q_[k] = (unsigned)(mag * SCALE_F);                               \
        }                                                                    \
        asm volatile("" :: "v"(q_[0]), "v"(q_[1]), "v"(q_[2]), "v"(q_[3])); \
        asm volatile("" :: "v"(X0), "v"(X1));                                \
    } while (0)

    v4u A0, A1, B0, B1, C0, C1;
    v4f AD, BDv, CD;
    GLOAD(A0, A1, AD, off);  off += stepB;
    GLOAD(B0, B1, BDv, off); off += stepB;
    int i = 0;
    #pragma unroll 1
    for (; i + 4 < nit; i += 3) {
        GLOAD(C0, C1, CD, off);  off += stepB;
        VWAIT(6); MBODY(A0, A1, AD);
        GLOAD(A0, A1, AD, off);  off += stepB;
        VWAIT(6); MBODY(B0, B1, BDv);
        GLOAD(B0, B1, BDv, off); off += stepB;
        VWAIT(6); MBODY(C0, C1, CD);
    }
    VWAIT(3); MBODY(A0, A1, AD);
    VWAIT(0); MBODY(B0, B1, BDv);
    #undef MBODY

    __syncthreads();
    unsigned keep = binsu[t & 4095] ^ packed[t & 16383];
    asm volatile("" :: "v"(keep));
}

// ---------------------------------------------------------------------------
// General fused kernel (non-conforming sizes), unchanged.
__global__ __launch_bounds__(NT, 8)
void srb_fused_u32_gen(const unsigned* __restrict__ packed_ws,
                       const int* __restrict__ ai,
                       const float* __restrict__ dist,
                       const float* __restrict__ pre_tab,
                       const float* __restrict__ dfac_tab,
                       unsigned long long* __restrict__ acc,
                       int P, int mol_shift) {
    __shared__ unsigned packed[16384];
    __shared__ unsigned binsu[4096];

    const int t = threadIdx.x;
    for (int i = t; i < 4096; i += NT) binsu[i] = 0u;
    const float myPre  = -pre_tab[t & 15];
    const float myDfac =  dfac_tab[t & 15];
    {
        int4* dst = (int4*)packed;
        const int4* src = (const int4*)packed_ws;
        for (int i = t; i < 4096; i += NT) dst[i] = src[i];
    }
    __syncthreads();

    const float a2b   = (float)1.8897261258369282;
    const float rc    = (float)(5.2 * 1.8897261258369282);
    const float rcinv = (float)(1.0 / (5.2 * 1.8897261258369282));

    const int ng     = P >> 2;
    const int stride = (int)gridDim.x * NT;
    const int4*   v0 = (const int4*)ai;
    const int4*   v1 = (const int4*)(ai + P);
    const float4* dv = (const float4*)dist;

    for (int g = (int)blockIdx.x * NT + t; g < ng; g += stride) {
        int4 I0 = v0[g], I1 = v1[g]; float4 D = dv[g];
        unsigned a0[4] = { (unsigned)I0.x, (unsigned)I0.y,
                           (unsigned)I0.z, (unsigned)I0.w };
        unsigned a1[4] = { (unsigned)I1.x, (unsigned)I1.y,
                           (unsigned)I1.z, (unsigned)I1.w };
        float    dd[4] = { D.x, D.y, D.z, D.w };
        unsigned w0[4], w1[4];
        #pragma unroll
        for (int k = 0; k < 4; ++k) w0[k] = packed[a0[k] >> 4];
        #pragma unroll
        for (int k = 0; k < 4; ++k) w1[k] = packed[a1[k] >> 4];
        float pr[4], df[4];
        #pragma unroll
        for (int k = 0; k < 4; ++k) {
            unsigned s0 = (w0[k] >> ((a0[k] & 15u) << 1)) & 3u;
            unsigned s1 = (w1[k] >> ((a1[k] & 15u) << 1)) & 3u;
            int idx = (int)((s0 << 2) | s1);
            pr[k] = __shfl(myPre,  idx, 64);
            df[k] = __shfl(myDfac, idx, 64);
        }
        unsigned q[4];
        #pragma unroll
        for (int k = 0; k < 4; ++k) {
            float db  = dd[k] * a2b;
            float x   = db * rcinv;
            float arg = df[k] * db + (1.0f - 1.0f / (1.0f - x * x));
            float mag = pr[k] * __expf(arg);
            mag = (db < rc) ? mag : 0.0f;
            q[k] = (unsigned)(mag * SCALE_F);
        }
        #pragma unroll
        for (int k = 0; k < 4; ++k)
            atomicAdd(&binsu[a0[k] >> mol_shift], q[k]);
    }

    __syncthreads();
    for (int i = t; i < 4096; i += NT) {
        unsigned v = binsu[i];
        if (v) atomicAdd(&acc[i], (unsigned long long)v);
    }
}

// ---------------------------------------------------------------------------
__global__ void final_kernel(const unsigned long long* __restrict__ acc,
                             const float* __restrict__ energies,
                             float* __restrict__ out_e, int n_mol) {
    int m = blockIdx.x * blockDim.x + threadIdx.x;
    if (m < n_mol)
        out_e[m] = energies[m] - (float)((double)acc[m] * INV_SCALE);
}

// ---------------------------------------------------------------------------
__global__ void init_out_fallback(const int* __restrict__ species,
                                  const float* __restrict__ energies,
                                  float* __restrict__ out,
                                  int n_species, int n_mol) {
    int i = blockIdx.x * blockDim.x + threadIdx.x;
    if (i < n_species) out[i] = (float)species[i];
    else if (i < n_species + n_mol) out[i] = energies[i - n_species];
}

__global__ __launch_bounds__(NT, 1)
void srb_fused_f32(const int* __restrict__ species,
                   const int* __restrict__ ai,
                   const float* __restrict__ dist,
                   const float* __restrict__ pre_tab,
                   const float* __restrict__ dfac_tab,
                   float* __restrict__ out_e,
                   int P, int mol_shift) {
    __shared__ unsigned packed[16384];
    __shared__ float bins[4096];
    __shared__ float2 tab[16];
    const int t = threadIdx.x;
    for (int i = t; i < 4096; i += NT) bins[i] = 0.0f;
    if (t < 16) tab[t] = make_float2(pre_tab[t], dfac_tab[t]);
    for (int w = t; w < 16384; w += NT) {
        const int4* p4 = (const int4*)(species + (w << 4));
        int4 a = p4[0], b = p4[1], c = p4[2], d = p4[3];
        unsigned v =
            (unsigned)(a.x & 3)        | ((unsigned)(a.y & 3) << 2)  |
            ((unsigned)(a.z & 3) << 4) | ((unsigned)(a.w & 3) << 6)  |
            ((unsigned)(b.x & 3) << 8) | ((unsigned)(b.y & 3) << 10) |
            ((unsigned)(b.z & 3) << 12)| ((unsigned)(b.w & 3) << 14) |
            ((unsigned)(c.x & 3) << 16)| ((unsigned)(c.y & 3) << 18) |
            ((unsigned)(c.z & 3) << 20)| ((unsigned)(c.w & 3) << 22) |
            ((unsigned)(d.x & 3) << 24)| ((unsigned)(d.y & 3) << 26) |
            ((unsigned)(d.z & 3) << 28)| ((unsigned)(d.w & 3) << 30);
        packed[w] = v;
    }
    __syncthreads();
    const float a2b   = (float)1.8897261258369282;
    const float rc    = (float)(5.2 * 1.8897261258369282);
    const float rcinv = (float)(1.0 / (5.2 * 1.8897261258369282));
    auto body = [&](int a0, int a1, float dang) {
        unsigned ua0 = (unsigned)a0, ua1 = (unsigned)a1;
        unsigned s0 = (packed[ua0 >> 4] >> ((ua0 & 15u) << 1)) & 3u;
        unsigned s1 = (packed[ua1 >> 4] >> ((ua1 & 15u) << 1)) & 3u;
        float2 td = tab[(s0 << 2) | s1];
        float db = dang * a2b;
        float x  = db * rcinv;
        float arg = td.y * db + (1.0f - 1.0f / (1.0f - x * x));
        float srb = td.x * __expf(arg);
        srb = (db < rc) ? srb : 0.0f;
        atomicAdd(&bins[ua0 >> mol_shift], srb);
    };
    const int nv = P >> 2, stride = (int)gridDim.x * NT;
    const int4* v0 = (const int4*)ai;
    const int4* v1 = (const int4*)(ai + P);
    const float4* dv = (const float4*)dist;
    for (int v = (int)blockIdx.x * NT + t; v < nv; v += stride) {
        int4 i0 = v0[v]; int4 i1 = v1[v]; float4 dd = dv[v];
        body(i0.x, i1.x, dd.x); body(i0.y, i1.y, dd.y);
        body(i0.z, i1.z, dd.z); body(i0.w, i1.w, dd.w);
    }
    __syncthreads();
    for (int i = t; i < 4096; i += NT) {
        float s = bins[i];
        if (s != 0.0f) atomicAdd(&out_e[i], s);
    }
}

// ---------------------------------------------------------------------------
extern "C" void kernel_launch(void* const* d_in, const int* in_sizes, int n_in,
                              void* d_out, int out_size, void* d_ws, size_t ws_size,
                              hipStream_t stream) {
    const int*   species  = (const int*)d_in[0];
    const float* energies = (const float*)d_in[1];
    const int*   ai       = (const int*)d_in[2];
    const float* dist     = (const float*)d_in[3];
    const float* pre_tab  = (const float*)d_in[4];
    const float* dfac_tab = (const float*)d_in[5];

    const int n_species = in_sizes[0];            // 262144
    const int n_mol     = in_sizes[1];            // 4096
    const int P         = in_sizes[3];            // 16777216
    const int n_atoms   = n_species / n_mol;      // 64

    int mol_shift = 0;
    while ((1 << mol_shift) < n_atoms) ++mol_shift; // 6

    float* out   = (float*)d_out;
    float* out_e = out + n_species;

    const int    nwords    = n_species / 16;              // 16384
    const size_t packed_sz = (size_t)nwords * 4;          // 64KB
    const size_t acc_sz    = (size_t)n_mol * 8;           // 32KB
    const size_t need      = packed_sz + acc_sz;

    if (ws_size >= need && (P & 3) == 0) {
        unsigned*           packed = (unsigned*)d_ws;
        unsigned long long* acc    = (unsigned long long*)((char*)d_ws + packed_sz);

        init_kernel<<<(n_species + 255) / 256, 256, 0, stream>>>(
            species, out, acc, n_species, n_mol);
        pack_species_kernel<<<(nwords + 255) / 256, 256, 0, stream>>>(
            species, packed, nwords);

        const int ng     = P >> 2;
        const int stride = NBLK * NT;                     // 524288
        const int nit    = ng / stride;                   // 8 on bench
        const bool pipe_ok = (ng % stride == 0) && (nit >= 2) && (nit % 3 == 2);

        if (pipe_ok) {
            srb_fused_u32_pipe<<<NBLK, NT, 0, stream>>>(
                packed, ai, dist, pre_tab, dfac_tab, acc, P, mol_shift, nit);
        } else {
            srb_fused_u32_gen<<<NBLK, NT, 0, stream>>>(
                packed, ai, dist, pre_tab, dfac_tab, acc, P, mol_shift);
        }
        final_kernel<<<(n_mol + 255) / 256, 256, 0, stream>>>(
            acc, energies, out_e, n_mol);

        // ---- ablation dispatches (no global writes; measurement only) ----
        if (pipe_ok) {
            abl_stream16<<<NBLK, NT, 0, stream>>>(packed, ai, dist, P, nit);
            abl_gds_nomath<<<NBLK, NT, 0, stream>>>(
                packed, ai, dist, pre_tab, dfac_tab, P, mol_shift, nit);
            abl_math_nods<<<NBLK, NT, 0, stream>>>(
                packed, ai, dist, pre_tab, dfac_tab, P, nit);
        }
    } else {
        init_out_fallback<<<(n_species + n_mol + 255) / 256, 256, 0, stream>>>(
            species, energies, out, n_species, n_mol);
        srb_fused_f32<<<NBLK, NT, 0, stream>>>(
            species, ai, dist, pre_tab, dfac_tab, out_e, P, mol_shift);
    }
}

// Round 6
// 253.267 us; speedup vs baseline: 1.3637x; 1.3637x over previous
//
#include <hip/hip_runtime.h>
#include <math.h>

// EnergySRB, R11: chunked 2-phase loop with collective drain.
// R10 ablation: stream-only / stream+DS / stream+math each ran at ~the
// 192MB streaming floor (sum 94.5us, each <84); the full kernel (84us) is
// the SUM of its parts -> the full dependency chain convoys the waves so
// phases serialize instead of overlapping. R5-R9 invariance explained:
// occupancy/pipeline-depth/cache-warmth change within-phase costs, not the
// convoy. Fix: choose the lockstep - GEMM-style 2-phase iteration:
//   GLOAD(next, asm-pinned) ; PBODY(cur) overlaps the flight ;
//   s_waitcnt vmcnt(0) ; __syncthreads()   <- ONE collective drain/iter
// Outstanding bytes capped at ~48KB/block (vs R9's ~290KB/CU queue bloat);
// the 2 resident blocks/CU alternate drain<->compute. Math bit-identical.

#define NT        1024
#define NBLK      512
#define SCALE_F   134217728.0f              // 2^27
#define INV_SCALE 7.450580596923828125e-9   // 2^-27, exact in double

typedef unsigned v4u __attribute__((ext_vector_type(4)));
typedef float    v4f __attribute__((ext_vector_type(4)));

// ---------------------------------------------------------------------------
__global__ void pack_species_kernel(const int* __restrict__ sp,
                                    unsigned* __restrict__ packed, int nwords) {
    int w = blockIdx.x * blockDim.x + threadIdx.x;
    if (w >= nwords) return;
    const int4* p4 = (const int4*)(sp + (w << 4));
    int4 a = p4[0], b = p4[1], c = p4[2], d = p4[3];
    unsigned v =
        (unsigned)(a.x & 3)        | ((unsigned)(a.y & 3) << 2)  |
        ((unsigned)(a.z & 3) << 4) | ((unsigned)(a.w & 3) << 6)  |
        ((unsigned)(b.x & 3) << 8) | ((unsigned)(b.y & 3) << 10) |
        ((unsigned)(b.z & 3) << 12)| ((unsigned)(b.w & 3) << 14) |
        ((unsigned)(c.x & 3) << 16)| ((unsigned)(c.y & 3) << 18) |
        ((unsigned)(c.z & 3) << 20)| ((unsigned)(c.w & 3) << 22) |
        ((unsigned)(d.x & 3) << 24)| ((unsigned)(d.y & 3) << 26) |
        ((unsigned)(d.z & 3) << 28)| ((unsigned)(d.w & 3) << 30);
    packed[w] = v;
}

// ---------------------------------------------------------------------------
__global__ void init_kernel(const int* __restrict__ species,
                            float* __restrict__ out,
                            unsigned long long* __restrict__ acc,
                            int n_species, int n_mol) {
    int i = blockIdx.x * blockDim.x + threadIdx.x;
    if (i < n_species) out[i] = (float)species[i];
    if (i < n_mol)     acc[i] = 0ull;
}

// ---------------------------------------------------------------------------
#define GLOAD(d0, d1, dd, OFF)                                              \
    asm volatile("global_load_dwordx4 %0, %3, %4\n\t"                        \
                 "global_load_dwordx4 %1, %3, %5\n\t"                        \
                 "global_load_dwordx4 %2, %3, %6"                            \
                 : "=&v"(d0), "=&v"(d1), "=&v"(dd)                           \
                 : "v"(OFF), "s"(pb0), "s"(pb1), "s"(pbd)                    \
                 : "memory")

#define VWAIT0()                                                             \
    do {                                                                     \
        asm volatile("s_waitcnt vmcnt(0)" ::: "memory");                     \
        __builtin_amdgcn_sched_barrier(0);                                   \
    } while (0)

// ---------------------------------------------------------------------------
// Chunked 2-phase kernel. Requires nit>=2 and nit even (launcher gates).
// Bench: nit = 8.
__global__ __launch_bounds__(NT, 8)
void srb_fused_u32_pipe(const unsigned* __restrict__ packed_ws,
                        const int* __restrict__ ai,     // [2, P]
                        const float* __restrict__ dist, // [P] angstrom
                        const float* __restrict__ pre_tab,
                        const float* __restrict__ dfac_tab,
                        unsigned long long* __restrict__ acc,
                        int P, int mol_shift, int nit) {
    __shared__ unsigned packed[16384]; // 64KB
    __shared__ unsigned binsu[4096];   // 16KB (total exactly 80KB)

    const int t = threadIdx.x;
    for (int i = t; i < 4096; i += NT) binsu[i] = 0u;

    const float myPre  = -pre_tab[t & 15];   // magnitude, > 0
    const float myDfac =  dfac_tab[t & 15];

    {
        int4* dst = (int4*)packed;
        const int4* src = (const int4*)packed_ws;
        for (int i = t; i < 4096; i += NT) dst[i] = src[i];
    }
    __syncthreads();

    const float a2b   = (float)1.8897261258369282;
    const float rc    = (float)(5.2 * 1.8897261258369282);
    const float rcinv = (float)(1.0 / (5.2 * 1.8897261258369282));

    const int      stride = (int)gridDim.x * NT;
    const unsigned stepB  = (unsigned)stride * 16u;
    unsigned off = (unsigned)((int)blockIdx.x * NT + t) * 16u;

    const char* pb0 = (const char*)ai;
    const char* pb1 = (const char*)(ai + P);
    const char* pbd = (const char*)dist;

    #define PBODY(X0, X1, XD)                                                \
    do {                                                                     \
        unsigned a0_[4] = { X0[0], X0[1], X0[2], X0[3] };                    \
        unsigned a1_[4] = { X1[0], X1[1], X1[2], X1[3] };                    \
        float    dd_[4] = { XD[0], XD[1], XD[2], XD[3] };                    \
        unsigned w0_[4], w1_[4];                                             \
        _Pragma("unroll")                                                    \
        for (int k = 0; k < 4; ++k) w0_[k] = packed[a0_[k] >> 4];            \
        _Pragma("unroll")                                                    \
        for (int k = 0; k < 4; ++k) w1_[k] = packed[a1_[k] >> 4];            \
        float pr_[4], df_[4];                                                \
        _Pragma("unroll")                                                    \
        for (int k = 0; k < 4; ++k) {                                        \
            unsigned s0 = (w0_[k] >> ((a0_[k] & 15u) << 1)) & 3u;            \
            unsigned s1 = (w1_[k] >> ((a1_[k] & 15u) << 1)) & 3u;            \
            int idx = (int)((s0 << 2) | s1);                                 \
            pr_[k] = __shfl(myPre,  idx, 64);                                \
            df_[k] = __shfl(myDfac, idx, 64);                                \
        }                                                                    \
        unsigned q_[4];                                                      \
        _Pragma("unroll")                                                    \
        for (int k = 0; k < 4; ++k) {                                        \
            float db  = dd_[k] * a2b;                                        \
            float x   = db * rcinv;                                          \
            float arg = df_[k] * db + (1.0f - 1.0f / (1.0f - x * x));        \
            float mag = pr_[k] * __expf(arg);                                \
            mag = (db < rc) ? mag : 0.0f;                                    \
            q_[k] = (unsigned)(mag * SCALE_F);                               \
        }                                                                    \
        _Pragma("unroll")                                                    \
        for (int k = 0; k < 4; ++k)                                          \
            atomicAdd(&binsu[a0_[k] >> mol_shift], q_[k]);                   \
    } while (0)

    v4u A0, A1, B0, B1;
    v4f AD, BDv;

    // prologue: group 0 loaded and drained collectively.
    GLOAD(A0, A1, AD, off); off += stepB;
    VWAIT0();
    __syncthreads();

    // steady state: issue next, compute current (overlaps flight),
    // ONE collective drain + barrier per iteration.
    #pragma unroll 1
    for (int i = 0; i + 2 <= nit; i += 2) {
        GLOAD(B0, B1, BDv, off); off += stepB;   // group i+1
        PBODY(A0, A1, AD);                       // group i
        VWAIT0();
        __syncthreads();

        if (i + 2 < nit) {                       // wave-uniform guard
            GLOAD(A0, A1, AD, off); off += stepB; // group i+2
        }
        PBODY(B0, B1, BDv);                      // group i+1
        VWAIT0();
        __syncthreads();
    }
    #undef PBODY

    __syncthreads();
    for (int i2 = t; i2 < 4096; i2 += NT) {
        unsigned v = binsu[i2];
        if (v) atomicAdd(&acc[i2], (unsigned long long)v);
    }
}

// ---------------------------------------------------------------------------
// General fused kernel (non-conforming sizes), unchanged.
__global__ __launch_bounds__(NT, 8)
void srb_fused_u32_gen(const unsigned* __restrict__ packed_ws,
                       const int* __restrict__ ai,
                       const float* __restrict__ dist,
                       const float* __restrict__ pre_tab,
                       const float* __restrict__ dfac_tab,
                       unsigned long long* __restrict__ acc,
                       int P, int mol_shift) {
    __shared__ unsigned packed[16384];
    __shared__ unsigned binsu[4096];

    const int t = threadIdx.x;
    for (int i = t; i < 4096; i += NT) binsu[i] = 0u;
    const float myPre  = -pre_tab[t & 15];
    const float myDfac =  dfac_tab[t & 15];
    {
        int4* dst = (int4*)packed;
        const int4* src = (const int4*)packed_ws;
        for (int i = t; i < 4096; i += NT) dst[i] = src[i];
    }
    __syncthreads();

    const float a2b   = (float)1.8897261258369282;
    const float rc    = (float)(5.2 * 1.8897261258369282);
    const float rcinv = (float)(1.0 / (5.2 * 1.8897261258369282));

    const int ng     = P >> 2;
    const int stride = (int)gridDim.x * NT;
    const int4*   v0 = (const int4*)ai;
    const int4*   v1 = (const int4*)(ai + P);
    const float4* dv = (const float4*)dist;

    for (int g = (int)blockIdx.x * NT + t; g < ng; g += stride) {
        int4 I0 = v0[g], I1 = v1[g]; float4 D = dv[g];
        unsigned a0[4] = { (unsigned)I0.x, (unsigned)I0.y,
                           (unsigned)I0.z, (unsigned)I0.w };
        unsigned a1[4] = { (unsigned)I1.x, (unsigned)I1.y,
                           (unsigned)I1.z, (unsigned)I1.w };
        float    dd[4] = { D.x, D.y, D.z, D.w };
        unsigned w0[4], w1[4];
        #pragma unroll
        for (int k = 0; k < 4; ++k) w0[k] = packed[a0[k] >> 4];
        #pragma unroll
        for (int k = 0; k < 4; ++k) w1[k] = packed[a1[k] >> 4];
        float pr[4], df[4];
        #pragma unroll
        for (int k = 0; k < 4; ++k) {
            unsigned s0 = (w0[k] >> ((a0[k] & 15u) << 1)) & 3u;
            unsigned s1 = (w1[k] >> ((a1[k] & 15u) << 1)) & 3u;
            int idx = (int)((s0 << 2) | s1);
            pr[k] = __shfl(myPre,  idx, 64);
            df[k] = __shfl(myDfac, idx, 64);
        }
        unsigned q[4];
        #pragma unroll
        for (int k = 0; k < 4; ++k) {
            float db  = dd[k] * a2b;
            float x   = db * rcinv;
            float arg = df[k] * db + (1.0f - 1.0f / (1.0f - x * x));
            float mag = pr[k] * __expf(arg);
            mag = (db < rc) ? mag : 0.0f;
            q[k] = (unsigned)(mag * SCALE_F);
        }
        #pragma unroll
        for (int k = 0; k < 4; ++k)
            atomicAdd(&binsu[a0[k] >> mol_shift], q[k]);
    }

    __syncthreads();
    for (int i = t; i < 4096; i += NT) {
        unsigned v = binsu[i];
        if (v) atomicAdd(&acc[i], (unsigned long long)v);
    }
}

// ---------------------------------------------------------------------------
__global__ void final_kernel(const unsigned long long* __restrict__ acc,
                             const float* __restrict__ energies,
                             float* __restrict__ out_e, int n_mol) {
    int m = blockIdx.x * blockDim.x + threadIdx.x;
    if (m < n_mol)
        out_e[m] = energies[m] - (float)((double)acc[m] * INV_SCALE);
}

// ---------------------------------------------------------------------------
__global__ void init_out_fallback(const int* __restrict__ species,
                                  const float* __restrict__ energies,
                                  float* __restrict__ out,
                                  int n_species, int n_mol) {
    int i = blockIdx.x * blockDim.x + threadIdx.x;
    if (i < n_species) out[i] = (float)species[i];
    else if (i < n_species + n_mol) out[i] = energies[i - n_species];
}

__global__ __launch_bounds__(NT, 1)
void srb_fused_f32(const int* __restrict__ species,
                   const int* __restrict__ ai,
                   const float* __restrict__ dist,
                   const float* __restrict__ pre_tab,
                   const float* __restrict__ dfac_tab,
                   float* __restrict__ out_e,
                   int P, int mol_shift) {
    __shared__ unsigned packed[16384];
    __shared__ float bins[4096];
    __shared__ float2 tab[16];
    const int t = threadIdx.x;
    for (int i = t; i < 4096; i += NT) bins[i] = 0.0f;
    if (t < 16) tab[t] = make_float2(pre_tab[t], dfac_tab[t]);
    for (int w = t; w < 16384; w += NT) {
        const int4* p4 = (const int4*)(species + (w << 4));
        int4 a = p4[0], b = p4[1], c = p4[2], d = p4[3];
        unsigned v =
            (unsigned)(a.x & 3)        | ((unsigned)(a.y & 3) << 2)  |
            ((unsigned)(a.z & 3) << 4) | ((unsigned)(a.w & 3) << 6)  |
            ((unsigned)(b.x & 3) << 8) | ((unsigned)(b.y & 3) << 10) |
            ((unsigned)(b.z & 3) << 12)| ((unsigned)(b.w & 3) << 14) |
            ((unsigned)(c.x & 3) << 16)| ((unsigned)(c.y & 3) << 18) |
            ((unsigned)(c.z & 3) << 20)| ((unsigned)(c.w & 3) << 22) |
            ((unsigned)(d.x & 3) << 24)| ((unsigned)(d.y & 3) << 26) |
            ((unsigned)(d.z & 3) << 28)| ((unsigned)(d.w & 3) << 30);
        packed[w] = v;
    }
    __syncthreads();
    const float a2b   = (float)1.8897261258369282;
    const float rc    = (float)(5.2 * 1.8897261258369282);
    const float rcinv = (float)(1.0 / (5.2 * 1.8897261258369282));
    auto body = [&](int a0, int a1, float dang) {
        unsigned ua0 = (unsigned)a0, ua1 = (unsigned)a1;
        unsigned s0 = (packed[ua0 >> 4] >> ((ua0 & 15u) << 1)) & 3u;
        unsigned s1 = (packed[ua1 >> 4] >> ((ua1 & 15u) << 1)) & 3u;
        float2 td = tab[(s0 << 2) | s1];
        float db = dang * a2b;
        float x  = db * rcinv;
        float arg = td.y * db + (1.0f - 1.0f / (1.0f - x * x));
        float srb = td.x * __expf(arg);
        srb = (db < rc) ? srb : 0.0f;
        atomicAdd(&bins[ua0 >> mol_shift], srb);
    };
    const int nv = P >> 2, stride = (int)gridDim.x * NT;
    const int4* v0 = (const int4*)ai;
    const int4* v1 = (const int4*)(ai + P);
    const float4* dv = (const float4*)dist;
    for (int v = (int)blockIdx.x * NT + t; v < nv; v += stride) {
        int4 i0 = v0[v]; int4 i1 = v1[v]; float4 dd = dv[v];
        body(i0.x, i1.x, dd.x); body(i0.y, i1.y, dd.y);
        body(i0.z, i1.z, dd.z); body(i0.w, i1.w, dd.w);
    }
    __syncthreads();
    for (int i = t; i < 4096; i += NT) {
        float s = bins[i];
        if (s != 0.0f) atomicAdd(&out_e[i], s);
    }
}

// ---------------------------------------------------------------------------
extern "C" void kernel_launch(void* const* d_in, const int* in_sizes, int n_in,
                              void* d_out, int out_size, void* d_ws, size_t ws_size,
                              hipStream_t stream) {
    const int*   species  = (const int*)d_in[0];
    const float* energies = (const float*)d_in[1];
    const int*   ai       = (const int*)d_in[2];
    const float* dist     = (const float*)d_in[3];
    const float* pre_tab  = (const float*)d_in[4];
    const float* dfac_tab = (const float*)d_in[5];

    const int n_species = in_sizes[0];            // 262144
    const int n_mol     = in_sizes[1];            // 4096
    const int P         = in_sizes[3];            // 16777216
    const int n_atoms   = n_species / n_mol;      // 64

    int mol_shift = 0;
    while ((1 << mol_shift) < n_atoms) ++mol_shift; // 6

    float* out   = (float*)d_out;
    float* out_e = out + n_species;

    const int    nwords    = n_species / 16;              // 16384
    const size_t packed_sz = (size_t)nwords * 4;          // 64KB
    const size_t acc_sz    = (size_t)n_mol * 8;           // 32KB
    const size_t need      = packed_sz + acc_sz;

    if (ws_size >= need && (P & 3) == 0) {
        unsigned*           packed = (unsigned*)d_ws;
        unsigned long long* acc    = (unsigned long long*)((char*)d_ws + packed_sz);

        init_kernel<<<(n_species + 255) / 256, 256, 0, stream>>>(
            species, out, acc, n_species, n_mol);
        pack_species_kernel<<<(nwords + 255) / 256, 256, 0, stream>>>(
            species, packed, nwords);

        const int ng     = P >> 2;
        const int stride = NBLK * NT;                     // 524288
        const int nit    = ng / stride;                   // 8 on bench
        const bool pipe_ok = (ng % stride == 0) && (nit >= 2) && ((nit & 1) == 0);

        if (pipe_ok) {
            srb_fused_u32_pipe<<<NBLK, NT, 0, stream>>>(
                packed, ai, dist, pre_tab, dfac_tab, acc, P, mol_shift, nit);
        } else {
            srb_fused_u32_gen<<<NBLK, NT, 0, stream>>>(
                packed, ai, dist, pre_tab, dfac_tab, acc, P, mol_shift);
        }
        final_kernel<<<(n_mol + 255) / 256, 256, 0, stream>>>(
            acc, energies, out_e, n_mol);
    } else {
        init_out_fallback<<<(n_species + n_mol + 255) / 256, 256, 0, stream>>>(
            species, energies, out, n_species, n_mol);
        srb_fused_f32<<<NBLK, NT, 0, stream>>>(
            species, ai, dist, pre_tab, dfac_tab, out_e, P, mol_shift);
    }
}